// Round 4
// baseline (371.601 us; speedup 1.0000x reference)
//
#include <hip/hip_runtime.h>
#include <hip/hip_bf16.h>
#include <stdint.h>

// Problem constants
constexpr int IN_DIM   = 2048;
constexpr int OUT_DIM  = 2048;
constexpr int BATCH    = 4096;
constexpr int KDIM     = 2 * IN_DIM;   // concatenated K: [xn | S] vs [scale_base | Wd]
constexpr float LN_EPS = 1e-5f;

// GEMM geometry: 256x256 tile, 8 waves (2M x 4N), per-wave 128x64,
// split-K x2 -> grid 16*8*2 = 256 blocks (1/CU, 2 waves/SIMD).
#define BM 256
#define BN 256
#define BKH 32                          // k-half staging granule
constexpr int KSPLIT = 2;
constexpr int K_PER  = KDIM / KSPLIT;   // 2048 per block
constexpr int NKH    = K_PER / BKH;     // 64 half-k phases
constexpr int SLOT   = BM * BKH;        // 8192 shorts = 16 KB per ring slot

typedef __attribute__((ext_vector_type(8))) short  short8;  // 8 x bf16 (4 VGPRs)
typedef __attribute__((ext_vector_type(4))) float  f32x4;   // MFMA accumulator

__device__ __forceinline__ unsigned short f2bf(float f) {
  __hip_bfloat16 h = __float2bfloat16(f);
  return *reinterpret_cast<unsigned short*>(&h);
}
__device__ __forceinline__ unsigned pack2bf(float a, float b) {
  return (unsigned)f2bf(a) | ((unsigned)f2bf(b) << 16);
}

__device__ __forceinline__ void gld_lds16(const unsigned short* g, unsigned short* l) {
  __builtin_amdgcn_global_load_lds(
      (const __attribute__((address_space(1))) void*)g,
      (__attribute__((address_space(3))) void*)l, 16, 0, 0);
}

// ---------------------------------------------------------------------------
// Kernel 1 (FUSED prep): [0,BATCH) LayerNorm+RBF rows; [BATCH,+PACK) B-pack;
// [+PACK,+PACK+ZERO) zero-init of out (needed for split-K atomic accumulate).
// ---------------------------------------------------------------------------
constexpr int SW_F4   = OUT_DIM * IN_DIM * 2;   // float4 count of spline_weight
constexpr int SB_F4   = OUT_DIM * IN_DIM / 4;   // float4 count of scale_base
constexpr int PACK_BLOCKS = (SW_F4 + SB_F4) / 256;
constexpr int ZERO_BLOCKS = (BATCH * OUT_DIM) / (256 * 16);  // 16 floats/thread

__global__ __launch_bounds__(256) void prep_kernel(
    const float* __restrict__ x, const float* __restrict__ lnw,
    const float* __restrict__ lnb, const float* __restrict__ betap,
    const float* __restrict__ grid, unsigned short* __restrict__ A,
    const float* __restrict__ sw, const float* __restrict__ sb,
    unsigned* __restrict__ Bu, float* __restrict__ outz)
{
  const int tid = threadIdx.x;
  if (blockIdx.x < BATCH) {
    // ----------------------- LayerNorm + RBF path -----------------------
    const int row = blockIdx.x;
    const float4* xr = reinterpret_cast<const float4*>(x + (size_t)row * IN_DIM);
    float4 v0 = xr[tid];
    float4 v1 = xr[tid + 256];
    float s = (v0.x + v0.y) + (v0.z + v0.w) + (v1.x + v1.y) + (v1.z + v1.w);
    float q = v0.x * v0.x + v0.y * v0.y + v0.z * v0.z + v0.w * v0.w
            + v1.x * v1.x + v1.y * v1.y + v1.z * v1.z + v1.w * v1.w;
    #pragma unroll
    for (int off = 32; off > 0; off >>= 1) {
      s += __shfl_down(s, off, 64);
      q += __shfl_down(q, off, 64);
    }
    __shared__ float red[10];
    const int lane = tid & 63, wv = tid >> 6;
    if (lane == 0) { red[wv] = s; red[4 + wv] = q; }
    __syncthreads();
    if (tid == 0) {
      float ts = (red[0] + red[1]) + (red[2] + red[3]);
      float tq = (red[4] + red[5]) + (red[6] + red[7]);
      float mu  = ts * (1.0f / IN_DIM);
      float var = tq * (1.0f / IN_DIM) - mu * mu;
      red[8] = mu;
      red[9] = rsqrtf(var + LN_EPS);
    }
    __syncthreads();
    const float mu = red[8], rs = red[9];
    const float beta = fminf(fmaxf(betap[0], 0.5f), 6.0f);
    float g[8];
    #pragma unroll
    for (int i = 0; i < 8; i++) g[i] = grid[i];
    const float4* w4 = reinterpret_cast<const float4*>(lnw);
    const float4* b4 = reinterpret_cast<const float4*>(lnb);
    unsigned short* Ar = A + (size_t)row * KDIM;
    #pragma unroll
    for (int h = 0; h < 2; h++) {
      const int idx = tid + h * 256;        // float4 index within the row
      float4 xv  = (h == 0) ? v0 : v1;
      float4 wv4 = w4[idx];
      float4 bv4 = b4[idx];
      float xa[4] = {xv.x, xv.y, xv.z, xv.w};
      float wa[4] = {wv4.x, wv4.y, wv4.z, wv4.w};
      float ba[4] = {bv4.x, bv4.y, bv4.z, bv4.w};
      float xn[4], S[4];
      #pragma unroll
      for (int c = 0; c < 4; c++) {
        float xnv = (xa[c] - mu) * rs * wa[c] + ba[c];
        xn[c] = xnv;
        float acc = 0.f;
        #pragma unroll
        for (int gg = 0; gg < 8; gg++) {
          float d = xnv - g[gg];
          acc += __expf(-beta * d * d);
        }
        S[c] = acc;
      }
      uint2 px, ps;
      px.x = pack2bf(xn[0], xn[1]);
      px.y = pack2bf(xn[2], xn[3]);
      ps.x = pack2bf(S[0], S[1]);
      ps.y = pack2bf(S[2], S[3]);
      *reinterpret_cast<uint2*>(Ar + idx * 4) = px;
      *reinterpret_cast<uint2*>(Ar + IN_DIM + idx * 4) = ps;
    }
  } else if (blockIdx.x < BATCH + PACK_BLOCKS) {
    // --------------------------- B-pack path ---------------------------
    const int g = (blockIdx.x - BATCH) * 256 + tid;
    const int lane = tid & 63;
    if (g < SW_F4) {
      float4 v = reinterpret_cast<const float4*>(sw)[g];
      float s = (v.x + v.y) + (v.z + v.w);
      s += __shfl_xor(s, 1, 64);               // full Wd[i] in both lanes of pair
      float hi = __shfl_down(s, 2, 64);        // Wd of i+1 for even-pair lanes
      if ((lane & 3) == 0) {
        const int i_lin = g >> 1;              // linear (o,i)
        const int o = i_lin >> 11;             // / IN_DIM
        const int i = i_lin & (IN_DIM - 1);
        Bu[(size_t)o * (KDIM / 2) + (IN_DIM / 2) + (i >> 1)] = pack2bf(s, hi);
      }
    } else {
      const int t = g - SW_F4;                 // [0, SB_F4)
      float4 v = reinterpret_cast<const float4*>(sb)[t];
      const int o  = t >> 9;                   // 512 float4 per sb row
      const int i4 = t & 511;
      uint2 u;
      u.x = pack2bf(v.x, v.y);
      u.y = pack2bf(v.z, v.w);
      *reinterpret_cast<uint2*>(&Bu[(size_t)o * (KDIM / 2) + i4 * 2]) = u;
    }
  } else {
    // ------------------------ out zero-init path ------------------------
    const int zb = blockIdx.x - BATCH - PACK_BLOCKS;
    float4 z = {0.f, 0.f, 0.f, 0.f};
    float4* o4 = reinterpret_cast<float4*>(outz) + ((size_t)zb * 256 + tid) * 4;
    o4[0] = z; o4[1] = z; o4[2] = z; o4[3] = z;
  }
}

// ---------------------------------------------------------------------------
// Kernel 2: C += A @ B^T (+bias from kk=0), split-K x2, bf16 MFMA.
// R4: UNPIN the phase. R3's manual lgkmcnt(0)+sched_barrier(0)+setprio before
// the MFMA cluster forced {LDS window | MFMA window} serialization (4050
// cyc/phase vs ~1100 each) -- rule #18 applies to inline-asm ds_reads only;
// ours are compiler-visible, and the compiler emits exact fine-grained
// lgkmcnt(4/3/1/0) interleave of reads into the MFMA cluster (m97/m201
// evidence). Manual waits remain ONLY where the compiler cannot track deps:
// counted vmcnt for the DMA ring (never 0 in steady state) + raw barriers.
// Ring/swizzle/epilogue unchanged from R3 (bank conflicts measured 0).
// ---------------------------------------------------------------------------
__global__ __launch_bounds__(512, 2) void gemm_kernel(
    const unsigned short* __restrict__ A, const unsigned short* __restrict__ Bm,
    const float* __restrict__ bias, float* __restrict__ out)
{
  __shared__ __align__(16) unsigned short As[4 * SLOT];   // 64 KB ring
  __shared__ __align__(16) unsigned short Bs[4 * SLOT];   // 64 KB ring
  const int tid  = threadIdx.x;
  const int lane = tid & 63;
  const int wv   = tid >> 6;        // 0..7
  const int wr   = wv >> 2;         // 0..1 : M band (128 rows)
  const int wc   = wv & 3;          // 0..3 : N band (64 cols)
  const int lrow = lane & 15;
  const int lkq  = lane >> 4;       // k-granule (0..3) within a 32-k half

  const int gid = blockIdx.x;
  const int xcd = gid & 7;
  const int j   = gid >> 3;                       // 0..31
  const int kk  = xcd >> 2;                       // split-K half
  const int m0  = (((xcd & 3) << 2) + (j >> 3)) * BM;   // m-panel 0..15
  const int n0  = (j & 7) * BN;                         // n-panel 0..7
  const int kbase = kk * K_PER;

  f32x4 acc[8][4] = {};

  // Staging: per slot, A = 16 KB = 16 wave-instrs (2/wave), B same.
  // Stored granule s of row r holds global granule s ^ ((r>>1)&3); staging
  // row = (lane>>2) within a 16-row stripe, so fetch granule =
  // (lane&3) ^ ((lane>>3)&3). Swizzle folded into the per-lane GLOBAL
  // address; LDS dest wave-uniform base + lane*16 [m104/m108].
  const unsigned short* Ag[2];
  const unsigned short* Bg[2];
  int ldsO[2];
  #pragma unroll
  for (int t = 0; t < 2; t++) {
    const int r = (wv * 2 + t) * 16 + (lane >> 2);
    const int g = (lane & 3) ^ ((lane >> 3) & 3);
    Ag[t]   = A  + (size_t)(m0 + r) * KDIM + kbase + g * 8;
    Bg[t]   = Bm + (size_t)(n0 + r) * KDIM + kbase + g * 8;
    ldsO[t] = (wv * 2 + t) * 512;
  }

  // Prologue: stage half-k slots 0,1,2 (12 loads); land slot 0 (vmcnt(8)).
  #pragma unroll
  for (int p = 0; p < 3; p++) {
    const int d = p * SLOT, kc = p * BKH;
    gld_lds16(Ag[0] + kc, &As[d + ldsO[0]]);
    gld_lds16(Ag[1] + kc, &As[d + ldsO[1]]);
    gld_lds16(Bg[0] + kc, &Bs[d + ldsO[0]]);
    gld_lds16(Bg[1] + kc, &Bs[d + ldsO[1]]);
  }
  asm volatile("s_waitcnt vmcnt(8)" ::: "memory");
  __builtin_amdgcn_s_barrier();
  asm volatile("" ::: "memory");

  const int swz  = (lkq ^ ((lrow >> 1) & 3)) << 3;   // row-PAIR XOR (conflict-free)
  const int aoff = (wr * 128 + lrow) * 32 + swz;
  const int boff = (wc * 64  + lrow) * 32 + swz;

  #pragma unroll 1
  for (int kh = 0; kh < NKH; kh++) {
    const int slot = (kh & 3) * SLOT;

    // Issue-early: stage slot kh+3 into ring pos (kh-1)&3 (freed by the
    // barrier at end of iter kh-1: all waves' reads of slot kh-1 completed
    // before their final MFMA, which precedes that barrier).
    if (kh + 3 < NKH) {
      const int d = ((kh + 3) & 3) * SLOT, kc = (kh + 3) * BKH;
      gld_lds16(Ag[0] + kc, &As[d + ldsO[0]]);
      gld_lds16(Ag[1] + kc, &As[d + ldsO[1]]);
      gld_lds16(Bg[0] + kc, &Bs[d + ldsO[0]]);
      gld_lds16(Bg[1] + kc, &Bs[d + ldsO[1]]);
    }

    // Fragment reads + MFMA cluster: NO manual waits / fences here -- the
    // compiler pipelines the 12 ds_read_b128 into the 32 MFMAs with exact
    // counted lgkmcnt, overlapping LDS latency with the matrix pipe.
    short8 af[8], bf[4];
    #pragma unroll
    for (int mi = 0; mi < 8; mi++)
      af[mi] = *reinterpret_cast<const short8*>(&As[slot + aoff + mi * 512]);
    #pragma unroll
    for (int ni = 0; ni < 4; ni++)
      bf[ni] = *reinterpret_cast<const short8*>(&Bs[slot + boff + ni * 512]);

    #pragma unroll
    for (int mi = 0; mi < 8; mi++)
      #pragma unroll
      for (int ni = 0; ni < 4; ni++)
        acc[mi][ni] = __builtin_amdgcn_mfma_f32_16x16x32_bf16(
            af[mi], bf[ni], acc[mi][ni], 0, 0, 0);

    // Counted boundary wait: slot kh+1 landed; slots kh+2, kh+3 in flight.
    if (kh < NKH - 3)       asm volatile("s_waitcnt vmcnt(8)" ::: "memory");
    else if (kh == NKH - 3) asm volatile("s_waitcnt vmcnt(4)" ::: "memory");
    else if (kh == NKH - 2) asm volatile("s_waitcnt vmcnt(0)" ::: "memory");
    __builtin_amdgcn_s_barrier();
    asm volatile("" ::: "memory");
  }

  // Epilogue: C/D layout col=lane&15, row=(lane>>4)*4+reg [m89/m91].
  // Split-K accumulate: out was zeroed; 2 commutative f32 atomic adds/elem
  // -> deterministic. kk=0 contributes the bias.
  const int rb = (lane >> 4) * 4;
  #pragma unroll
  for (int ni = 0; ni < 4; ni++) {
    const int col = n0 + wc * 64 + ni * 16 + lrow;
    const float bv = (kk == 0) ? bias[col] : 0.0f;
    #pragma unroll
    for (int mi = 0; mi < 8; mi++) {
      const int rowm = m0 + wr * 128 + mi * 16 + rb;
      #pragma unroll
      for (int r = 0; r < 4; r++)
        atomicAdd(&out[(size_t)(rowm + r) * OUT_DIM + col], acc[mi][ni][r] + bv);
    }
  }
}

// ---------------------------------------------------------------------------
extern "C" void kernel_launch(void* const* d_in, const int* in_sizes, int n_in,
                              void* d_out, int out_size, void* d_ws, size_t ws_size,
                              hipStream_t stream) {
  const float* x    = (const float*)d_in[0];
  const float* lnw  = (const float*)d_in[1];
  const float* lnb  = (const float*)d_in[2];
  const float* sw   = (const float*)d_in[3];   // (OUT, IN, 8)
  const float* sb   = (const float*)d_in[4];   // (OUT, IN)
  const float* bias = (const float*)d_in[5];   // (OUT,)
  const float* beta = (const float*)d_in[6];   // (1,)
  const float* grid = (const float*)d_in[7];   // (8,)
  float* out = (float*)d_out;

  unsigned short* A = (unsigned short*)d_ws;               // BATCH x KDIM bf16 (33.5 MB)
  unsigned short* B = A + (size_t)BATCH * KDIM;            // OUT   x KDIM bf16 (16.8 MB)

  hipLaunchKernelGGL(prep_kernel, dim3(BATCH + PACK_BLOCKS + ZERO_BLOCKS), dim3(256), 0,
                     stream, x, lnw, lnb, beta, grid, A, sw, sb, (unsigned*)B, out);
  hipLaunchKernelGGL(gemm_kernel,
                     dim3((BATCH / BM) * (OUT_DIM / BN) * KSPLIT), dim3(512), 0, stream,
                     A, B, bias, out);
}

// Round 5
// 322.438 us; speedup vs baseline: 1.1525x; 1.1525x over previous
//
#include <hip/hip_runtime.h>
#include <hip/hip_bf16.h>
#include <stdint.h>

// Problem constants
constexpr int IN_DIM   = 2048;
constexpr int OUT_DIM  = 2048;
constexpr int BATCH    = 4096;
constexpr int KDIM     = 2 * IN_DIM;   // concatenated K: [xn | S] vs [scale_base | Wd]
constexpr float LN_EPS = 1e-5f;

// R5: R0 structure (measured best, 78.5 us gemm) with BK 64->32.
// LDS per block 64 KB -> 32 KB => 4 blocks/CU (launch_bounds(256,4)) vs 2.
// Rationale: all schedule variants (R0/R1/R3/R4) land at the same ~875 TF;
// regime is latency/barrier-stall bound (MfmaUtil 34 + VALUBusy 17, no BW
// ceiling near). m132 showed blocks/CU is the operative variable in this
// structure (BK 128: 3->2 blocks halved perf); we move it the other way.
#define TILE 128
#define BK   32
constexpr int NK    = KDIM / BK;       // 128 k-steps
constexpr int STAGE = TILE * BK;       // 4096 shorts per matrix per stage (8 KB)

typedef __attribute__((ext_vector_type(8))) short  short8;  // 8 x bf16 (4 VGPRs)
typedef __attribute__((ext_vector_type(4))) float  f32x4;   // MFMA accumulator

__device__ __forceinline__ unsigned short f2bf(float f) {
  __hip_bfloat16 h = __float2bfloat16(f);
  return *reinterpret_cast<unsigned short*>(&h);
}
__device__ __forceinline__ unsigned pack2bf(float a, float b) {
  return (unsigned)f2bf(a) | ((unsigned)f2bf(b) << 16);
}

// ---------------------------------------------------------------------------
// Kernel 1 (FUSED prep): blocks [0, BATCH) do LayerNorm+RBF rows;
// blocks [BATCH, BATCH + (SW_F4+SB_F4)/256) do the B-pack.
// (Exact round-0 version: direct-store gemm needs no zero-init.)
// ---------------------------------------------------------------------------
constexpr int SW_F4   = OUT_DIM * IN_DIM * 2;   // float4 count of spline_weight
constexpr int SB_F4   = OUT_DIM * IN_DIM / 4;   // float4 count of scale_base
constexpr int PACK_BLOCKS = (SW_F4 + SB_F4) / 256;

__global__ __launch_bounds__(256) void prep_kernel(
    const float* __restrict__ x, const float* __restrict__ lnw,
    const float* __restrict__ lnb, const float* __restrict__ betap,
    const float* __restrict__ grid, unsigned short* __restrict__ A,
    const float* __restrict__ sw, const float* __restrict__ sb,
    unsigned* __restrict__ Bu)    // B as uint (2 bf16 per uint), OUT x KDIM/2
{
  const int tid = threadIdx.x;
  if (blockIdx.x < BATCH) {
    // ----------------------- LayerNorm + RBF path -----------------------
    const int row = blockIdx.x;
    const float4* xr = reinterpret_cast<const float4*>(x + (size_t)row * IN_DIM);
    float4 v0 = xr[tid];
    float4 v1 = xr[tid + 256];
    float s = (v0.x + v0.y) + (v0.z + v0.w) + (v1.x + v1.y) + (v1.z + v1.w);
    float q = v0.x * v0.x + v0.y * v0.y + v0.z * v0.z + v0.w * v0.w
            + v1.x * v1.x + v1.y * v1.y + v1.z * v1.z + v1.w * v1.w;
    #pragma unroll
    for (int off = 32; off > 0; off >>= 1) {
      s += __shfl_down(s, off, 64);
      q += __shfl_down(q, off, 64);
    }
    __shared__ float red[10];
    const int lane = tid & 63, wv = tid >> 6;
    if (lane == 0) { red[wv] = s; red[4 + wv] = q; }
    __syncthreads();
    if (tid == 0) {
      float ts = (red[0] + red[1]) + (red[2] + red[3]);
      float tq = (red[4] + red[5]) + (red[6] + red[7]);
      float mu  = ts * (1.0f / IN_DIM);
      float var = tq * (1.0f / IN_DIM) - mu * mu;
      red[8] = mu;
      red[9] = rsqrtf(var + LN_EPS);
    }
    __syncthreads();
    const float mu = red[8], rs = red[9];
    const float beta = fminf(fmaxf(betap[0], 0.5f), 6.0f);
    float g[8];
    #pragma unroll
    for (int i = 0; i < 8; i++) g[i] = grid[i];
    const float4* w4 = reinterpret_cast<const float4*>(lnw);
    const float4* b4 = reinterpret_cast<const float4*>(lnb);
    unsigned short* Ar = A + (size_t)row * KDIM;
    #pragma unroll
    for (int h = 0; h < 2; h++) {
      const int idx = tid + h * 256;        // float4 index within the row
      float4 xv  = (h == 0) ? v0 : v1;
      float4 wv4 = w4[idx];
      float4 bv4 = b4[idx];
      float xa[4] = {xv.x, xv.y, xv.z, xv.w};
      float wa[4] = {wv4.x, wv4.y, wv4.z, wv4.w};
      float ba[4] = {bv4.x, bv4.y, bv4.z, bv4.w};
      float xn[4], S[4];
      #pragma unroll
      for (int c = 0; c < 4; c++) {
        float xnv = (xa[c] - mu) * rs * wa[c] + ba[c];
        xn[c] = xnv;
        float acc = 0.f;
        #pragma unroll
        for (int gg = 0; gg < 8; gg++) {
          float d = xnv - g[gg];
          acc += __expf(-beta * d * d);
        }
        S[c] = acc;
      }
      uint2 px, ps;
      px.x = pack2bf(xn[0], xn[1]);
      px.y = pack2bf(xn[2], xn[3]);
      ps.x = pack2bf(S[0], S[1]);
      ps.y = pack2bf(S[2], S[3]);
      *reinterpret_cast<uint2*>(Ar + idx * 4) = px;
      *reinterpret_cast<uint2*>(Ar + IN_DIM + idx * 4) = ps;
    }
  } else {
    // --------------------------- B-pack path ---------------------------
    const int g = (blockIdx.x - BATCH) * 256 + tid;
    const int lane = tid & 63;
    if (g < SW_F4) {
      float4 v = reinterpret_cast<const float4*>(sw)[g];
      float s = (v.x + v.y) + (v.z + v.w);
      s += __shfl_xor(s, 1, 64);               // full Wd[i] in both lanes of pair
      float hi = __shfl_down(s, 2, 64);        // Wd of i+1 for even-pair lanes
      if ((lane & 3) == 0) {
        const int i_lin = g >> 1;              // linear (o,i)
        const int o = i_lin >> 11;             // / IN_DIM
        const int i = i_lin & (IN_DIM - 1);
        Bu[(size_t)o * (KDIM / 2) + (IN_DIM / 2) + (i >> 1)] = pack2bf(s, hi);
      }
    } else {
      const int t = g - SW_F4;                 // [0, SB_F4)
      float4 v = reinterpret_cast<const float4*>(sb)[t];
      const int o  = t >> 9;                   // 512 float4 per sb row
      const int i4 = t & 511;
      uint2 u;
      u.x = pack2bf(v.x, v.y);
      u.y = pack2bf(v.z, v.w);
      *reinterpret_cast<uint2*>(&Bu[(size_t)o * (KDIM / 2) + i4 * 2]) = u;
    }
  }
}

// ---------------------------------------------------------------------------
// Kernel 2: C = A @ B^T + bias.  M=BATCH, N=OUT_DIM, K=KDIM, bf16 MFMA.
// R0 structure exactly (128x128 tile, 4 waves as 2x2 of 64x64, dbuf LDS,
// global_load_lds width=16, one __syncthreads per k-step, XCD supertile
// swizzle, direct store) -- only BK 64->32 for 4 blocks/CU occupancy.
// LDS row stride is now 64 B: bank-conflict-freedom uses the R3-VERIFIED
// row-pair XOR (measured SQ_LDS_BANK_CONFLICT = 0): stored granule s of row
// r holds global granule s ^ ((r>>1)&3); 8-lane beat covers (parity,granule)
// = all 32 banks exactly once; 8 lanes per 4-bank group = the exact 8-cyc
// b128 floor.
// ---------------------------------------------------------------------------
__device__ __forceinline__ void gld_lds16(const unsigned short* g, unsigned short* l) {
  __builtin_amdgcn_global_load_lds(
      (const __attribute__((address_space(1))) void*)g,
      (__attribute__((address_space(3))) void*)l, 16, 0, 0);
}

__global__ __launch_bounds__(256, 4) void gemm_kernel(
    const unsigned short* __restrict__ A, const unsigned short* __restrict__ Bm,
    const float* __restrict__ bias, float* __restrict__ out)
{
  __shared__ __align__(16) unsigned short As[2 * STAGE];   // 16 KB
  __shared__ __align__(16) unsigned short Bs[2 * STAGE];   // 16 KB
  const int tid  = threadIdx.x;
  const int lane = tid & 63;
  const int wv   = tid >> 6;
  const int wr   = wv >> 1;        // 2x2 wave grid over the 128x128 tile
  const int wc   = wv & 1;
  // XCD supertile swizzle (R0-exact): block d -> XCD d%8; each XCD's 64
  // blocks form an 8x8 (bm,bn) square for L2 locality.
  const int gid = blockIdx.x;
  const int sq  = gid & 7;
  const int q   = gid >> 3;
  const int m0  = ((sq >> 1) * 8 + (q >> 3)) * TILE;   // bm in [0,32)
  const int n0  = ((sq & 1) * 8 + (q & 7)) * TILE;     // bn in [0,16)
  const int lrow = lane & 15;      // fragment m / n index
  const int lkq  = lane >> 4;      // k-granule (0..3) within a 32-k step

  f32x4 acc[4][4] = {};

  // Staging: 512 16-B segments per matrix per stage; seg s -> LDS slot s
  // (linear; DMA dest is wave-uniform base + lane*16 [m104/m108]).
  // Slot (row = s>>2, g' = s&3) holds global granule g' ^ ((row>>1)&3)
  // (swizzle folded into the GLOBAL fetch address).
  const unsigned short* Ap[2];
  const unsigned short* Bp[2];
  unsigned short* ldsA[2];
  unsigned short* ldsB[2];
  #pragma unroll
  for (int j = 0; j < 2; j++) {
    const int seg  = j * 256 + wv * 64 + lane;
    const int row  = seg >> 2;
    const int gcol = ((seg & 3) ^ ((seg >> 3) & 3)) * 8;   // ((row>>1)&3) xor
    Ap[j] = A  + (size_t)(m0 + row) * KDIM + gcol;
    Bp[j] = Bm + (size_t)(n0 + row) * KDIM + gcol;
    ldsA[j] = &As[(j * 256 + wv * 64) * 8];
    ldsB[j] = &Bs[(j * 256 + wv * 64) * 8];
  }

  // Prologue: stage 0 into buffer 0.
  #pragma unroll
  for (int j = 0; j < 2; j++) gld_lds16(Ap[j], ldsA[j]);
  #pragma unroll
  for (int j = 0; j < 2; j++) gld_lds16(Bp[j], ldsB[j]);

  #pragma unroll 1
  for (int kt = 0; kt < NK; kt++) {
    __syncthreads();               // drains stage-kt loads (issued a stage ago)
    const int cur = (kt & 1) * STAGE;
    if (kt + 1 < NK) {             // wave-uniform; prefetch stage kt+1
      const int nxt = ((kt + 1) & 1) * STAGE;
      const int koff = (kt + 1) * BK;
      #pragma unroll
      for (int j = 0; j < 2; j++) gld_lds16(Ap[j] + koff, ldsA[j] + nxt);
      #pragma unroll
      for (int j = 0; j < 2; j++) gld_lds16(Bp[j] + koff, ldsB[j] + nxt);
    }

    const int swz = (lkq ^ ((lrow >> 1) & 3)) * 8;   // row-pair XOR (verified 0-conflict)
    short8 af[4], bf[4];
    #pragma unroll
    for (int mi = 0; mi < 4; mi++) {
      const int r = wr * 64 + mi * 16 + lrow;
      af[mi] = *reinterpret_cast<const short8*>(&As[cur + r * BK + swz]);
    }
    #pragma unroll
    for (int ni = 0; ni < 4; ni++) {
      const int r = wc * 64 + ni * 16 + lrow;
      bf[ni] = *reinterpret_cast<const short8*>(&Bs[cur + r * BK + swz]);
    }
    #pragma unroll
    for (int mi = 0; mi < 4; mi++)
      #pragma unroll
      for (int ni = 0; ni < 4; ni++)
        acc[mi][ni] = __builtin_amdgcn_mfma_f32_16x16x32_bf16(
            af[mi], bf[ni], acc[mi][ni], 0, 0, 0);
  }

  // Epilogue: C/D layout col=lane&15, row=(lane>>4)*4+reg  [measured m89/m91]
  const int rb = (lane >> 4) * 4;
  #pragma unroll
  for (int ni = 0; ni < 4; ni++) {
    const int col = n0 + wc * 64 + ni * 16 + lrow;
    const float bv = bias[col];
    #pragma unroll
    for (int mi = 0; mi < 4; mi++) {
      const int rowm = m0 + wr * 64 + mi * 16 + rb;
      #pragma unroll
      for (int r = 0; r < 4; r++)
        out[(size_t)(rowm + r) * OUT_DIM + col] = acc[mi][ni][r] + bv;
    }
  }
}

// ---------------------------------------------------------------------------
extern "C" void kernel_launch(void* const* d_in, const int* in_sizes, int n_in,
                              void* d_out, int out_size, void* d_ws, size_t ws_size,
                              hipStream_t stream) {
  const float* x    = (const float*)d_in[0];
  const float* lnw  = (const float*)d_in[1];
  const float* lnb  = (const float*)d_in[2];
  const float* sw   = (const float*)d_in[3];   // (OUT, IN, 8)
  const float* sb   = (const float*)d_in[4];   // (OUT, IN)
  const float* bias = (const float*)d_in[5];   // (OUT,)
  const float* beta = (const float*)d_in[6];   // (1,)
  const float* grid = (const float*)d_in[7];   // (8,)
  float* out = (float*)d_out;

  unsigned short* A = (unsigned short*)d_ws;               // BATCH x KDIM bf16 (33.5 MB)
  unsigned short* B = A + (size_t)BATCH * KDIM;            // OUT   x KDIM bf16 (16.8 MB)

  hipLaunchKernelGGL(prep_kernel, dim3(BATCH + PACK_BLOCKS), dim3(256), 0, stream,
                     x, lnw, lnb, beta, grid, A, sw, sb, (unsigned*)B);
  hipLaunchKernelGGL(gemm_kernel, dim3((BATCH / TILE) * (OUT_DIM / TILE)), dim3(256), 0, stream,
                     A, B, bias, out);
}

// Round 6
// 308.974 us; speedup vs baseline: 1.2027x; 1.0436x over previous
//
#include <hip/hip_runtime.h>
#include <hip/hip_bf16.h>
#include <stdint.h>

// Problem constants
constexpr int IN_DIM   = 2048;
constexpr int OUT_DIM  = 2048;
constexpr int BATCH    = 4096;
constexpr int KDIM     = 2 * IN_DIM;   // concatenated K: [xn | S] vs [scale_base | Wd]
constexpr float LN_EPS = 1e-5f;

#define TILE 128
#define BK   64
constexpr int NK    = KDIM / BK;       // 64 k-steps
constexpr int STAGE = TILE * BK;       // shorts per matrix per stage (16 KB)

typedef __attribute__((ext_vector_type(8))) short  short8;  // 8 x bf16 (4 VGPRs)
typedef __attribute__((ext_vector_type(4))) float  f32x4;   // MFMA accumulator

__device__ __forceinline__ unsigned short f2bf(float f) {
  __hip_bfloat16 h = __float2bfloat16(f);
  return *reinterpret_cast<unsigned short*>(&h);
}
__device__ __forceinline__ unsigned pack2bf(float a, float b) {
  return (unsigned)f2bf(a) | ((unsigned)f2bf(b) << 16);
}

// ---------------------------------------------------------------------------
// Kernel 1 (prep, RESTRUCTURED for latency/MLP; math identical to verified):
//   blocks [0, LN_BLOCKS): LayerNorm+RBF, ONE WAVE PER ROW (4 rows/block).
//     No __syncthreads, no LDS, no serial section: full-row sum/sumsq via
//     6-step __shfl_xor butterfly (all lanes end with the result).
//   blocks [LN_BLOCKS, +SW_BLOCKS): sw-pack, one (o,i) entry per thread
//     (2 float4 = 32 B read, in-thread sum of 8, one shfl, 1-of-2-lane
//     coalesced uint store).
//   blocks [.., +SB_BLOCKS): sb-pack (unchanged).
// ---------------------------------------------------------------------------
constexpr int LN_BLOCKS = BATCH / 4;                     // 1024 (4 rows/block)
constexpr int SW_BLOCKS = (OUT_DIM * IN_DIM) / 256;      // 16384
constexpr int SB_F4     = OUT_DIM * IN_DIM / 4;
constexpr int SB_BLOCKS = SB_F4 / 256;                   // 4096

__global__ __launch_bounds__(256) void prep_kernel(
    const float* __restrict__ x, const float* __restrict__ lnw,
    const float* __restrict__ lnb, const float* __restrict__ betap,
    const float* __restrict__ grid, unsigned short* __restrict__ A,
    const float* __restrict__ sw, const float* __restrict__ sb,
    unsigned* __restrict__ Bu)    // B as uint (2 bf16 per uint), OUT x KDIM/2
{
  const int tid  = threadIdx.x;
  const int lane = tid & 63;
  if (blockIdx.x < LN_BLOCKS) {
    // ------------- LayerNorm + RBF path: one wave per row -------------
    const int wv  = tid >> 6;
    const int row = blockIdx.x * 4 + wv;
    const float4* xr = reinterpret_cast<const float4*>(x + (size_t)row * IN_DIM);
    float4 xv[8];
    #pragma unroll
    for (int i = 0; i < 8; i++) xv[i] = xr[i * 64 + lane];   // coalesced
    float s = 0.f, q = 0.f;
    #pragma unroll
    for (int i = 0; i < 8; i++) {
      s += (xv[i].x + xv[i].y) + (xv[i].z + xv[i].w);
      q += xv[i].x * xv[i].x + xv[i].y * xv[i].y
         + xv[i].z * xv[i].z + xv[i].w * xv[i].w;
    }
    #pragma unroll
    for (int off = 32; off > 0; off >>= 1) {   // butterfly: all lanes get total
      s += __shfl_xor(s, off, 64);
      q += __shfl_xor(q, off, 64);
    }
    const float mu  = s * (1.0f / IN_DIM);
    const float var = q * (1.0f / IN_DIM) - mu * mu;
    const float rs  = rsqrtf(var + LN_EPS);
    const float beta = fminf(fmaxf(betap[0], 0.5f), 6.0f);
    float g[8];
    #pragma unroll
    for (int i = 0; i < 8; i++) g[i] = grid[i];
    const float4* w4 = reinterpret_cast<const float4*>(lnw);
    const float4* b4 = reinterpret_cast<const float4*>(lnb);
    unsigned short* Ar = A + (size_t)row * KDIM;
    #pragma unroll
    for (int i = 0; i < 8; i++) {
      const int idx = i * 64 + lane;          // float4 index within the row
      float4 wv4 = w4[idx];
      float4 bv4 = b4[idx];
      float xa[4] = {xv[i].x, xv[i].y, xv[i].z, xv[i].w};
      float wa[4] = {wv4.x, wv4.y, wv4.z, wv4.w};
      float ba[4] = {bv4.x, bv4.y, bv4.z, bv4.w};
      float xn[4], S[4];
      #pragma unroll
      for (int c = 0; c < 4; c++) {
        float xnv = (xa[c] - mu) * rs * wa[c] + ba[c];
        xn[c] = xnv;
        float acc = 0.f;
        #pragma unroll
        for (int gg = 0; gg < 8; gg++) {
          float d = xnv - g[gg];
          acc += __expf(-beta * d * d);
        }
        S[c] = acc;
      }
      uint2 px, ps;
      px.x = pack2bf(xn[0], xn[1]);
      px.y = pack2bf(xn[2], xn[3]);
      ps.x = pack2bf(S[0], S[1]);
      ps.y = pack2bf(S[2], S[3]);
      *reinterpret_cast<uint2*>(Ar + idx * 4) = px;
      *reinterpret_cast<uint2*>(Ar + IN_DIM + idx * 4) = ps;
    }
  } else if (blockIdx.x < LN_BLOCKS + SW_BLOCKS) {
    // ---------------- sw-pack: one (o,i) entry per thread ----------------
    const int t = (blockIdx.x - LN_BLOCKS) * 256 + tid;    // linear (o,i)
    const float4* sw4 = reinterpret_cast<const float4*>(sw);
    float4 v0 = sw4[t * 2];
    float4 v1 = sw4[t * 2 + 1];
    float s = ((v0.x + v0.y) + (v0.z + v0.w)) + ((v1.x + v1.y) + (v1.z + v1.w));
    float hi = __shfl_down(s, 1, 64);          // Wd of i+1 for even lanes
    if ((lane & 1) == 0) {
      const int o = t >> 11;                   // / IN_DIM
      const int i = t & (IN_DIM - 1);
      Bu[(size_t)o * (KDIM / 2) + (IN_DIM / 2) + (i >> 1)] = pack2bf(s, hi);
    }
  } else {
    // --------------------------- sb-pack path ---------------------------
    const int t = (blockIdx.x - LN_BLOCKS - SW_BLOCKS) * 256 + tid;  // [0, SB_F4)
    float4 v = reinterpret_cast<const float4*>(sb)[t];
    const int o  = t >> 9;                     // 512 float4 per sb row
    const int i4 = t & 511;
    uint2 u;
    u.x = pack2bf(v.x, v.y);
    u.y = pack2bf(v.z, v.w);
    *reinterpret_cast<uint2*>(&Bu[(size_t)o * (KDIM / 2) + i4 * 2]) = u;
  }
}

// ---------------------------------------------------------------------------
// Kernel 2: C = A @ B^T + bias.  M=BATCH, N=OUT_DIM, K=KDIM, bf16 MFMA.
// EXACT round-0 kernel (measured best: ~875 TF main loop). 128x128 tile,
// BK=64, 256 thr / 4 waves (2x2 of 64x64), XOR-swizzled LDS,
// global_load_lds width=16, double-buffered stages, one barrier per k-step,
// XCD supertile swizzle.
// ---------------------------------------------------------------------------
__device__ __forceinline__ void gld_lds16(const unsigned short* g, unsigned short* l) {
  __builtin_amdgcn_global_load_lds(
      (const __attribute__((address_space(1))) void*)g,
      (__attribute__((address_space(3))) void*)l, 16, 0, 0);
}

__global__ __launch_bounds__(256) void gemm_kernel(
    const unsigned short* __restrict__ A, const unsigned short* __restrict__ Bm,
    const float* __restrict__ bias, float* __restrict__ out)
{
  __shared__ __align__(16) unsigned short As[2 * STAGE];   // 32 KB
  __shared__ __align__(16) unsigned short Bs[2 * STAGE];   // 32 KB
  const int tid  = threadIdx.x;
  const int lane = tid & 63;
  const int wv   = tid >> 6;
  const int wr   = wv >> 1;        // 2x2 wave grid over the 128x128 tile
  const int wc   = wv & 1;
  // XCD supertile swizzle
  const int gid = blockIdx.x;
  const int sq  = gid & 7;
  const int q   = gid >> 3;
  const int m0  = ((sq >> 1) * 8 + (q >> 3)) * TILE;   // bm in [0,32)
  const int n0  = ((sq & 1) * 8 + (q & 7)) * TILE;     // bn in [0,16)
  const int lrow = lane & 15;      // fragment m / n index
  const int lkq  = lane >> 4;      // k-quarter within a 16-B-granule row

  f32x4 acc[4][4] = {};

  // Staging: 1024 16-B segments per matrix per stage; seg s -> LDS slot s;
  // slot (row = s>>3, col8' = s&7) holds global col8 = col8' ^ (row&7)
  // (swizzle folded into the GLOBAL fetch address; LDS dest is wave-uniform
  // base + lane*16 [m104/m108]).
  const unsigned short* Ap[4];
  const unsigned short* Bp[4];
  unsigned short* ldsA[4];
  unsigned short* ldsB[4];
  #pragma unroll
  for (int j = 0; j < 4; j++) {
    const int seg  = j * 256 + wv * 64 + lane;
    const int row  = seg >> 3;
    const int gcol = ((seg & 7) ^ (row & 7)) * 8;
    Ap[j] = A  + (size_t)(m0 + row) * KDIM + gcol;
    Bp[j] = Bm + (size_t)(n0 + row) * KDIM + gcol;
    ldsA[j] = &As[(j * 256 + wv * 64) * 8];
    ldsB[j] = &Bs[(j * 256 + wv * 64) * 8];
  }

  // Prologue: stage 0 into buffer 0.
  #pragma unroll
  for (int j = 0; j < 4; j++) gld_lds16(Ap[j], ldsA[j]);
  #pragma unroll
  for (int j = 0; j < 4; j++) gld_lds16(Bp[j], ldsB[j]);

  #pragma unroll 1
  for (int kt = 0; kt < NK; kt++) {
    __syncthreads();               // drains stage-kt loads (issued a stage ago)
    const int cur = (kt & 1) * STAGE;
    if (kt + 1 < NK) {             // wave-uniform; prefetch stage kt+1
      const int nxt = ((kt + 1) & 1) * STAGE;
      const int koff = (kt + 1) * BK;
      #pragma unroll
      for (int j = 0; j < 4; j++) gld_lds16(Ap[j] + koff, ldsA[j] + nxt);
      #pragma unroll
      for (int j = 0; j < 4; j++) gld_lds16(Bp[j] + koff, ldsB[j] + nxt);
    }

    short8 af[2][4], bf[2][4];
    #pragma unroll
    for (int h = 0; h < 2; h++) {
      #pragma unroll
      for (int mi = 0; mi < 4; mi++) {
        const int r = wr * 64 + mi * 16 + lrow;
        af[h][mi] = *reinterpret_cast<const short8*>(
            &As[cur + r * BK + (((h << 2) | lkq) ^ (lrow & 7)) * 8]);
      }
      #pragma unroll
      for (int ni = 0; ni < 4; ni++) {
        const int r = wc * 64 + ni * 16 + lrow;
        bf[h][ni] = *reinterpret_cast<const short8*>(
            &Bs[cur + r * BK + (((h << 2) | lkq) ^ (lrow & 7)) * 8]);
      }
    }
    #pragma unroll
    for (int h = 0; h < 2; h++)
      #pragma unroll
      for (int mi = 0; mi < 4; mi++)
        #pragma unroll
        for (int ni = 0; ni < 4; ni++)
          acc[mi][ni] = __builtin_amdgcn_mfma_f32_16x16x32_bf16(
              af[h][mi], bf[h][ni], acc[mi][ni], 0, 0, 0);
  }

  // Epilogue: C/D layout col=lane&15, row=(lane>>4)*4+reg  [measured m89/m91]
  const int rb = (lane >> 4) * 4;
  #pragma unroll
  for (int ni = 0; ni < 4; ni++) {
    const int col = n0 + wc * 64 + ni * 16 + lrow;
    const float bv = bias[col];
    #pragma unroll
    for (int mi = 0; mi < 4; mi++) {
      const int rowm = m0 + wr * 64 + mi * 16 + rb;
      #pragma unroll
      for (int r = 0; r < 4; r++)
        out[(size_t)(rowm + r) * OUT_DIM + col] = acc[mi][ni][r] + bv;
    }
  }
}

// ---------------------------------------------------------------------------
extern "C" void kernel_launch(void* const* d_in, const int* in_sizes, int n_in,
                              void* d_out, int out_size, void* d_ws, size_t ws_size,
                              hipStream_t stream) {
  const float* x    = (const float*)d_in[0];
  const float* lnw  = (const float*)d_in[1];
  const float* lnb  = (const float*)d_in[2];
  const float* sw   = (const float*)d_in[3];   // (OUT, IN, 8)
  const float* sb   = (const float*)d_in[4];   // (OUT, IN)
  const float* bias = (const float*)d_in[5];   // (OUT,)
  const float* beta = (const float*)d_in[6];   // (1,)
  const float* grid = (const float*)d_in[7];   // (8,)
  float* out = (float*)d_out;

  unsigned short* A = (unsigned short*)d_ws;               // BATCH x KDIM bf16 (33.5 MB)
  unsigned short* B = A + (size_t)BATCH * KDIM;            // OUT   x KDIM bf16 (16.8 MB)

  hipLaunchKernelGGL(prep_kernel, dim3(LN_BLOCKS + SW_BLOCKS + SB_BLOCKS), dim3(256), 0,
                     stream, x, lnw, lnb, beta, grid, A, sw, sb, (unsigned*)B);
  hipLaunchKernelGGL(gemm_kernel, dim3((BATCH / TILE) * (OUT_DIM / TILE)), dim3(256), 0, stream,
                     A, B, bias, out);
}